// Round 1
// baseline (323.170 us; speedup 1.0000x reference)
//
#include <hip/hip_runtime.h>

#define TOPK 32
#define EMB 64

// One 16-lane group per node. Each lane owns a float4 slice (16B) of the
// 64-float embedding row -> every neighbor-row gather is a fully coalesced
// 256B segment (16 lanes x dwordx4). Weights/indices: 2 per lane, broadcast
// via __shfl width=16.
//
// Reference math: w = (wei != 0) row-normalized => out = sum(masked rows)/cnt.
__global__ __launch_bounds__(256) void pprgo_kernel(
    const float* __restrict__ emb,
    const float* __restrict__ wei,
    const int*   __restrict__ nei,
    float*       __restrict__ out,
    int n_nodes)
{
    const int tid     = blockIdx.x * blockDim.x + threadIdx.x;
    const int group   = tid >> 4;        // global node index (one node per group)
    const int lane    = tid & 15;        // 0..15 within group
    const int n_groups = (gridDim.x * blockDim.x) >> 4;

    for (int n = group; n < n_nodes; n += n_groups) {
        // Per-lane: two (weight, index) pairs covering k = lane and k = lane+16.
        const long base = (long)n * TOPK;
        const float w0 = wei[base + lane];
        const float w1 = wei[base + 16 + lane];
        const int   i0 = nei[base + lane];
        const int   i1 = nei[base + 16 + lane];
        const float m0 = (w0 != 0.0f) ? 1.0f : 0.0f;
        const float m1 = (w1 != 0.0f) ? 1.0f : 0.0f;

        float4 acc = make_float4(0.f, 0.f, 0.f, 0.f);
        float  cnt = 0.0f;

        #pragma unroll 8
        for (int k = 0; k < 16; ++k) {
            const int   j0 = __shfl(i0, k, 16);
            const float a0 = __shfl(m0, k, 16);
            const float4 r0 = *(const float4*)(emb + (size_t)j0 * EMB + lane * 4);
            acc.x += a0 * r0.x;  acc.y += a0 * r0.y;
            acc.z += a0 * r0.z;  acc.w += a0 * r0.w;
            cnt += a0;

            const int   j1 = __shfl(i1, k, 16);
            const float a1 = __shfl(m1, k, 16);
            const float4 r1 = *(const float4*)(emb + (size_t)j1 * EMB + lane * 4);
            acc.x += a1 * r1.x;  acc.y += a1 * r1.y;
            acc.z += a1 * r1.z;  acc.w += a1 * r1.w;
            cnt += a1;
        }

        const float s = 1.0f / (cnt + 1e-12f);
        float4 o;
        o.x = acc.x * s; o.y = acc.y * s; o.z = acc.z * s; o.w = acc.w * s;
        *(float4*)(out + (size_t)n * EMB + lane * 4) = o;
    }
}

extern "C" void kernel_launch(void* const* d_in, const int* in_sizes, int n_in,
                              void* d_out, int out_size, void* d_ws, size_t ws_size,
                              hipStream_t stream) {
    const float* emb = (const float*)d_in[0];   // [N, 64] fp32
    const float* wei = (const float*)d_in[1];   // [N, 32] fp32
    const int*   nei = (const int*)d_in[2];     // [N, 32] int
    float*       out = (float*)d_out;           // [N, 1, 64] fp32

    const int n_nodes = in_sizes[1] / TOPK;     // 200000
    const int groups_per_block = 256 / 16;      // 16 nodes per block
    const int blocks = (n_nodes + groups_per_block - 1) / groups_per_block;

    pprgo_kernel<<<blocks, 256, 0, stream>>>(emb, wei, nei, out, n_nodes);
}

// Round 2
// 233.698 us; speedup vs baseline: 1.3829x; 1.3829x over previous
//
#include <hip/hip_runtime.h>
#include <hip/hip_fp16.h>

#define TOPK 32
#define EMB 64

// ---------------- Pass 1: fp32 table -> fp16 table in workspace ----------------
__global__ __launch_bounds__(256) void cvt_f32_to_f16(
    const float* __restrict__ src, __half* __restrict__ dst, int total4)
{
    int i = blockIdx.x * blockDim.x + threadIdx.x;   // one float4 per thread
    if (i < total4) {
        float4 v = ((const float4*)src)[i];
        __half2 h0 = __floats2half2_rn(v.x, v.y);
        __half2 h1 = __floats2half2_rn(v.z, v.w);
        ((__half2*)dst)[i * 2]     = h0;
        ((__half2*)dst)[i * 2 + 1] = h1;
    }
}

// ---------------- Main: fp16 gather, 8-lane groups, batched loads ----------------
// One 8-lane group per node; lane owns 8 consecutive halfs (16 B) of the 64-wide
// row, so each row gather = 8 lanes x dwordx4 = 128 B coalesced. 8 gathered rows
// kept in flight per batch (32 VGPRs of load data) for memory-level parallelism.
__global__ __launch_bounds__(256) void pprgo_h_kernel(
    const __half* __restrict__ emb,
    const float*  __restrict__ wei,
    const int*    __restrict__ nei,
    float*        __restrict__ out,
    int n_nodes)
{
    const int tid  = blockIdx.x * blockDim.x + threadIdx.x;
    const int n    = tid >> 3;          // node index (8 lanes per node)
    const int lane = tid & 7;
    if (n >= n_nodes) return;

    const long base = (long)n * TOPK;
    float w[4]; int idx[4];
    #pragma unroll
    for (int t = 0; t < 4; ++t) {       // k = t*8 + lane
        w[t]   = wei[base + t * 8 + lane];
        idx[t] = nei[base + t * 8 + lane];
    }
    float m[4];
    #pragma unroll
    for (int t = 0; t < 4; ++t) m[t] = (w[t] != 0.0f) ? 1.0f : 0.0f;

    float acc[8] = {0.f, 0.f, 0.f, 0.f, 0.f, 0.f, 0.f, 0.f};
    float cnt = 0.0f;

    #pragma unroll
    for (int t = 0; t < 4; ++t) {
        // broadcast this batch's 8 indices + masks to all lanes of the group
        int   j[8]; float a[8];
        #pragma unroll
        for (int k = 0; k < 8; ++k) {
            j[k] = __shfl(idx[t], k, 8);
            a[k] = __shfl(m[t],   k, 8);
        }
        // issue all 8 row loads (16 B each) before consuming any
        float4 r[8];
        #pragma unroll
        for (int k = 0; k < 8; ++k) {
            r[k] = *(const float4*)(emb + (size_t)j[k] * EMB + lane * 8);
        }
        #pragma unroll
        for (int k = 0; k < 8; ++k) {
            const __half2* hp = (const __half2*)&r[k];
            #pragma unroll
            for (int q = 0; q < 4; ++q) {
                float2 f = __half22float2(hp[q]);
                acc[q * 2]     += a[k] * f.x;
                acc[q * 2 + 1] += a[k] * f.y;
            }
            cnt += a[k];
        }
    }

    const float s = 1.0f / (cnt + 1e-12f);
    float4 o0, o1;
    o0.x = acc[0] * s; o0.y = acc[1] * s; o0.z = acc[2] * s; o0.w = acc[3] * s;
    o1.x = acc[4] * s; o1.y = acc[5] * s; o1.z = acc[6] * s; o1.w = acc[7] * s;
    float* op = out + (size_t)n * EMB + lane * 8;
    *(float4*)op       = o0;
    *(float4*)(op + 4) = o1;
}

// ---------------- Fallback: verified R0 fp32 kernel (if ws too small) ----------------
__global__ __launch_bounds__(256) void pprgo_f32_kernel(
    const float* __restrict__ emb,
    const float* __restrict__ wei,
    const int*   __restrict__ nei,
    float*       __restrict__ out,
    int n_nodes)
{
    const int tid   = blockIdx.x * blockDim.x + threadIdx.x;
    const int group = tid >> 4;
    const int lane  = tid & 15;
    if (group >= n_nodes) return;
    const int n = group;
    const long base = (long)n * TOPK;
    const float w0 = wei[base + lane];
    const float w1 = wei[base + 16 + lane];
    const int   i0 = nei[base + lane];
    const int   i1 = nei[base + 16 + lane];
    const float m0 = (w0 != 0.0f) ? 1.0f : 0.0f;
    const float m1 = (w1 != 0.0f) ? 1.0f : 0.0f;
    float4 acc = make_float4(0.f, 0.f, 0.f, 0.f);
    float  cnt = 0.0f;
    #pragma unroll 8
    for (int k = 0; k < 16; ++k) {
        const int   j0 = __shfl(i0, k, 16);
        const float a0 = __shfl(m0, k, 16);
        const float4 r0 = *(const float4*)(emb + (size_t)j0 * EMB + lane * 4);
        acc.x += a0 * r0.x; acc.y += a0 * r0.y; acc.z += a0 * r0.z; acc.w += a0 * r0.w;
        cnt += a0;
        const int   j1 = __shfl(i1, k, 16);
        const float a1 = __shfl(m1, k, 16);
        const float4 r1 = *(const float4*)(emb + (size_t)j1 * EMB + lane * 4);
        acc.x += a1 * r1.x; acc.y += a1 * r1.y; acc.z += a1 * r1.z; acc.w += a1 * r1.w;
        cnt += a1;
    }
    const float s = 1.0f / (cnt + 1e-12f);
    float4 o;
    o.x = acc.x * s; o.y = acc.y * s; o.z = acc.z * s; o.w = acc.w * s;
    *(float4*)(out + (size_t)n * EMB + lane * 4) = o;
}

extern "C" void kernel_launch(void* const* d_in, const int* in_sizes, int n_in,
                              void* d_out, int out_size, void* d_ws, size_t ws_size,
                              hipStream_t stream) {
    const float* emb = (const float*)d_in[0];   // [N, 64] fp32
    const float* wei = (const float*)d_in[1];   // [N, 32] fp32
    const int*   nei = (const int*)d_in[2];     // [N, 32] int
    float*       out = (float*)d_out;           // [N, 1, 64] fp32

    const int n_nodes = in_sizes[1] / TOPK;     // 200000
    const size_t need = (size_t)n_nodes * EMB * sizeof(__half);  // 25.6 MB

    if (ws_size >= need) {
        __half* embh = (__half*)d_ws;
        const int total4 = n_nodes * EMB / 4;               // float4 count
        const int cvt_blocks = (total4 + 255) / 256;
        cvt_f32_to_f16<<<cvt_blocks, 256, 0, stream>>>(emb, embh, total4);

        const int threads = n_nodes * 8;                    // 8 lanes per node
        const int blocks = (threads + 255) / 256;
        pprgo_h_kernel<<<blocks, 256, 0, stream>>>(embh, wei, nei, out, n_nodes);
    } else {
        const int threads = n_nodes * 16;
        const int blocks = (threads + 255) / 256;
        pprgo_f32_kernel<<<blocks, 256, 0, stream>>>(emb, wei, nei, out, n_nodes);
    }
}